// Round 2
// baseline (167.731 us; speedup 1.0000x reference)
//
#include <hip/hip_runtime.h>

typedef float f32x4 __attribute__((ext_vector_type(4)));
typedef short bf16x8 __attribute__((ext_vector_type(8)));   // 8 bf16 in 4 VGPRs (MFMA A/B operand)
typedef unsigned short u16x4 __attribute__((ext_vector_type(4)));

#define NS 8192
#define NB 16
#define NE 128
#define GS 4   // s-values per block (one per wave)

// Pack two f32 -> two bf16 (round-half-up via +0x8000, then v_perm grabs high halves).
__device__ __forceinline__ unsigned pack_bf16_rn(float lo, float hi) {
  union { float f; unsigned u; } a, b; a.f = lo; b.f = hi;
  return __builtin_amdgcn_perm(b.u + 0x8000u, a.u + 0x8000u, 0x07060302u);
}
// 8 consecutive f32 -> one MFMA bf16x8 fragment (2x dwordx4 load + 8 add + 4 perm)
__device__ __forceinline__ bf16x8 frag_from_f32(const float* p) {
  f32x4 lo = *(const f32x4*)p;
  f32x4 hi = *(const f32x4*)(p + 4);
  union { bf16x8 v; unsigned u[4]; } r;
  r.u[0] = pack_bf16_rn(lo[0], lo[1]);
  r.u[1] = pack_bf16_rn(lo[2], lo[3]);
  r.u[2] = pack_bf16_rn(hi[0], hi[1]);
  r.u[3] = pack_bf16_rn(hi[2], hi[3]);
  return r.v;
}
__device__ __forceinline__ u16x4 pack4(f32x4 v) {
  union { u16x4 s; unsigned u[2]; } r;
  r.u[0] = pack_bf16_rn(v[0], v[1]);
  r.u[1] = pack_bf16_rn(v[2], v[3]);
  return r.s;
}

__global__ __launch_bounds__(256, 2)
void nsa_fused(const float* __restrict__ x,
               const float* __restrict__ Wk,
               const float* __restrict__ bk,
               const float* __restrict__ Wv,
               const float* __restrict__ bv,
               float* __restrict__ out)
{
  // Kt/Vt: [mat(2)][s(GS)][e(128)][b(16)] bf16; row = 32B -> b64-packed writes, b128 frag reads
  __shared__ __align__(16) unsigned short kt[2 * GS * NE * 16];
  // P buffer per wave: [16 e][136 f] bf16 (pad 8)
  __shared__ __align__(16) unsigned short pbuf[4 * 16 * 136];
  __shared__ __align__(16) unsigned short zbuf[32];   // 64B zeros: K-dim padding (b=16..31)

  const int tid  = threadIdx.x;
  const int wave = tid >> 6;
  const int lane = tid & 63;
  const int q    = lane >> 4;    // quad 0..3
  const int ln   = lane & 15;
  const int s0   = blockIdx.x * GS;

  if (tid < 32) zbuf[tid] = 0;

  bf16x8 xof[4];   // A-frags for the out-GEMM (this wave's own s), captured in KV phase

  // ---------------- KV phase: K = X@Wk^T + bk, V = X@Wv^T + bv ----------------
  // wave w owns e-tiles {2w, 2w+1}; weight B-frags held in registers for all 4 s.
  {
    const float* const Wm[2] = { Wk, Wv };
    bf16x8 wf[2][2][4];   // [mat][ntl][ks]
    float  bias[2][2];
    #pragma unroll
    for (int mat = 0; mat < 2; ++mat)
      #pragma unroll
      for (int ntl = 0; ntl < 2; ++ntl) {
        const int e = (wave * 2 + ntl) * 16 + ln;
        #pragma unroll
        for (int ks = 0; ks < 4; ++ks)
          // B[k][n=e] = W[e][k]: 8 consecutive f32 from W row e
          wf[mat][ntl][ks] = frag_from_f32(Wm[mat] + e * NE + ks * 32 + q * 8);
      }
    #pragma unroll
    for (int ntl = 0; ntl < 2; ++ntl) {
      const int e = (wave * 2 + ntl) * 16 + ln;
      bias[0][ntl] = bk[e];
      bias[1][ntl] = bv[e];
    }

    for (int mt = 0; mt < GS; ++mt) {            // m-tile = one s (16 b-rows)
      const int s = s0 + mt;
      bf16x8 xf[4];
      #pragma unroll
      for (int ks = 0; ks < 4; ++ks)             // A[m=b][k]: 8 f32 from x row b
        xf[ks] = frag_from_f32(x + (s * NB + ln) * NE + ks * 32 + q * 8);
      if (mt == wave) {
        #pragma unroll
        for (int ks = 0; ks < 4; ++ks) xof[ks] = xf[ks];
      }
      #pragma unroll
      for (int mat = 0; mat < 2; ++mat)
        #pragma unroll
        for (int ntl = 0; ntl < 2; ++ntl) {
          f32x4 acc = { bias[mat][ntl], bias[mat][ntl], bias[mat][ntl], bias[mat][ntl] };
          #pragma unroll
          for (int ks = 0; ks < 4; ++ks)
            acc = __builtin_amdgcn_mfma_f32_16x16x32_bf16(xf[ks], wf[mat][ntl][ks], acc, 0, 0, 0);
          // C/D: col=e (lane&15), rows b=q*4+r -> packed write to Kt/Vt[e][b]
          const int e = (wave * 2 + ntl) * 16 + ln;
          *(u16x4*)&kt[((mat * GS + mt) * NE + e) * 16 + q * 4] = pack4(acc);
        }
    }
  }
  __syncthreads();

  // ---------------- attention phase: wave handles s = s0 + wave ----------------
  {
    const int sw  = s0 + wave;
    const int smt = wave;

    // A-frags for scores^T = V^T K: A[m=f][k=b] = Vt[f][b]; pad b>=16 with zeros
    bf16x8 vf[8];
    #pragma unroll
    for (int mt = 0; mt < 8; ++mt) {
      const int f = mt * 16 + ln;
      const unsigned short* src = (q < 2) ? &kt[((GS + smt) * NE + f) * 16 + q * 8] : zbuf;
      vf[mt] = *(const bf16x8*)src;
    }

    unsigned short* pw = &pbuf[wave * 16 * 136];
    const float scale = 1.4426950408889634f / 90.50966799187809f;  // log2(e)/sqrt(8192)

    for (int eb = 0; eb < 8; ++eb) {
      const int e = eb * 16 + ln;
      // B-frag: B[k=b][n=e] = Kt[e][b]
      const unsigned short* ksrc = (q < 2) ? &kt[(smt * NE + e) * 16 + q * 8] : zbuf;
      const bf16x8 kf = *(const bf16x8*)ksrc;

      f32x4 sc[8];   // lane(ln,q) reg r = scores[e=16eb+ln][f=16mt+4q+r]
      #pragma unroll
      for (int mt = 0; mt < 8; ++mt) {
        const f32x4 z = { 0.f, 0.f, 0.f, 0.f };
        sc[mt] = __builtin_amdgcn_mfma_f32_16x16x32_bf16(vf[mt], kf, z, 0, 0, 0);
      }

      // softmax over f for fixed e: 32 in-lane values + reduce across quads (xor 16,32)
      float mx = -3.4e38f;
      #pragma unroll
      for (int mt = 0; mt < 8; ++mt)
        #pragma unroll
        for (int r = 0; r < 4; ++r) mx = fmaxf(mx, sc[mt][r]);
      mx = fmaxf(mx, __shfl_xor(mx, 16));
      mx = fmaxf(mx, __shfl_xor(mx, 32));
      float sum = 0.f;
      #pragma unroll
      for (int mt = 0; mt < 8; ++mt)
        #pragma unroll
        for (int r = 0; r < 4; ++r) {
          const float p = __builtin_amdgcn_exp2f((sc[mt][r] - mx) * scale);
          sc[mt][r] = p;
          sum += p;
        }
      sum += __shfl_xor(sum, 16);
      sum += __shfl_xor(sum, 32);
      const float inv_l = __builtin_amdgcn_rcpf(sum);

      // P rows for this e-block -> LDS row-major P[e][f]; 4 consecutive f per reg-group
      #pragma unroll
      for (int mt = 0; mt < 8; ++mt)
        *(u16x4*)&pw[ln * 136 + mt * 16 + q * 4] = pack4(sc[mt]);

      // out n-tile eb: D[m=b][n=e] = sum_f X[b][f] * P[e][f]
      f32x4 oacc = { 0.f, 0.f, 0.f, 0.f };
      #pragma unroll
      for (int ks = 0; ks < 4; ++ks) {
        const bf16x8 pf = *(const bf16x8*)&pw[ln * 136 + ks * 32 + q * 8];
        oacc = __builtin_amdgcn_mfma_f32_16x16x32_bf16(xof[ks], pf, oacc, 0, 0, 0);
      }
      #pragma unroll
      for (int r = 0; r < 4; ++r)
        out[(sw * NB + q * 4 + r) * NE + e] = oacc[r] * inv_l;
    }
  }
}

extern "C" void kernel_launch(void* const* d_in, const int* in_sizes, int n_in,
                              void* d_out, int out_size, void* d_ws, size_t ws_size,
                              hipStream_t stream)
{
  const float* x  = (const float*)d_in[0];
  const float* Wk = (const float*)d_in[1];
  const float* bk = (const float*)d_in[2];
  const float* Wv = (const float*)d_in[3];
  const float* bv = (const float*)d_in[4];
  float* o = (float*)d_out;

  dim3 grid(NS / GS), block(256);
  hipLaunchKernelGGL(nsa_fused, grid, block, 0, stream, x, Wk, bk, Wv, bv, o);
}